// Round 1
// baseline (263.750 us; speedup 1.0000x reference)
//
#include <hip/hip_runtime.h>

// Problem constants
// B=16, TQ=256, TK=256, QD=512, KD=512
// d_out = [ tanh_out: 16*256*512 f32 ; p: 16*256*256 f32 ]

__device__ __forceinline__ float fast_rcp(float x) { return __builtin_amdgcn_rcpf(x); }

// ---------------------------------------------------------------------------
// K1/K4: fp32 tiled GEMM with bias (+ optional tanh epilogue).
// C[M][N] = act(A[M][K] @ Bm[K][N] + bias[N]); A is split at kSplit between
// A0 and A1 (both with row stride lda) to implement concat([query, context]).
// 64x64 tile, BK=16, 256 threads, 4x4 per-thread microtile.
// ---------------------------------------------------------------------------
__global__ __launch_bounds__(256) void gemm_bias_f32(
    const float* __restrict__ A0, const float* __restrict__ A1, int kSplit, int lda,
    const float* __restrict__ Bm, const float* __restrict__ bias,
    float* __restrict__ C, int N, int K, int do_tanh)
{
  __shared__ float As[16][68];
  __shared__ float Bs[16][68];
  const int t = threadIdx.x;
  const int tx = t & 15, ty = t >> 4;
  const int col0 = blockIdx.x * 64, row0 = blockIdx.y * 64;
  const int lr = t >> 2, lk = (t & 3) << 2;     // A-load: row 0..63, k 0/4/8/12
  const int bkr = t >> 4, bkc = (t & 15) << 2;  // B-load: k 0..15, col group
  float acc[4][4] = {};

  for (int k0 = 0; k0 < K; k0 += 16) {
    const float* Asrc = (k0 < kSplit) ? A0 : A1;
    const int kc = ((k0 < kSplit) ? k0 : (k0 - kSplit)) + lk;
    float4 a4 = *(const float4*)&Asrc[(size_t)(row0 + lr) * lda + kc];
    float4 b4 = *(const float4*)&Bm[(size_t)(k0 + bkr) * N + col0 + bkc];
    __syncthreads();
    As[lk + 0][lr] = a4.x; As[lk + 1][lr] = a4.y;
    As[lk + 2][lr] = a4.z; As[lk + 3][lr] = a4.w;
    *(float4*)&Bs[bkr][bkc] = b4;
    __syncthreads();
#pragma unroll
    for (int kk = 0; kk < 16; ++kk) {
      float4 av = *(const float4*)&As[kk][ty * 4];
      float4 bv = *(const float4*)&Bs[kk][tx * 4];
      float am[4] = {av.x, av.y, av.z, av.w};
      float bm[4] = {bv.x, bv.y, bv.z, bv.w};
#pragma unroll
      for (int i = 0; i < 4; ++i)
#pragma unroll
        for (int j = 0; j < 4; ++j)
          acc[i][j] = fmaf(am[i], bm[j], acc[i][j]);
    }
  }

  float4 bb = *(const float4*)&bias[col0 + tx * 4];
  float bias4[4] = {bb.x, bb.y, bb.z, bb.w};
#pragma unroll
  for (int i = 0; i < 4; ++i) {
    float4 o;
    float* op = &o.x;
#pragma unroll
    for (int j = 0; j < 4; ++j) {
      float v = acc[i][j] + bias4[j];
      if (do_tanh) {
        float e = __expf(2.0f * v);            // tanh(v) = 1 - 2/(e^{2v}+1)
        v = 1.0f - 2.0f * fast_rcp(e + 1.0f);  // safe at +/-inf
      }
      op[j] = v;
    }
    *(float4*)&C[(size_t)(row0 + ty * 4 + i) * N + col0 + tx * 4] = o;
  }
}

// ---------------------------------------------------------------------------
// K2: scores[b,q,k] = sum_n w[n]*tanh(aq[b,q,n]+keys[b,k,n]) + b_att
// Block = 16 q x 16 k tile, one thread per (q,k) pair, full dot over n=512
// in 4 chunks of 128 staged in LDS (pre-scaled by 2 for the exp(2x) form).
// ---------------------------------------------------------------------------
__global__ __launch_bounds__(256) void score_kernel(
    const float* __restrict__ aq,    // [4096][512]
    const float* __restrict__ keys,  // [16][256][512]
    const float* __restrict__ w_att, // [512]
    const float* __restrict__ b_att, // [1]
    float* __restrict__ scores)      // [16][256][256]
{
  __shared__ float aq_s[16][132];
  __shared__ float key_s[16][132];
  __shared__ float w_s[512];

  const int b = blockIdx.z, q0 = blockIdx.y * 16, k0 = blockIdx.x * 16;
  const int t = threadIdx.x;
  w_s[t] = w_att[t];
  w_s[t + 256] = w_att[t + 256];

  const int qi = t >> 4, ki = t & 15;
  const int lr = t >> 4, li = t & 15;  // staging row / col-group
  const float* aqp = aq + (size_t)(b * 256 + q0) * 512;
  const float* kp = keys + (size_t)(b * 256 + k0) * 512;

  float acc = 0.0f;
  for (int c = 0; c < 4; ++c) {
    const int base = lr * 512 + c * 128 + li * 8;
    float4 a0 = *(const float4*)&aqp[base];
    float4 a1 = *(const float4*)&aqp[base + 4];
    float4 kv0 = *(const float4*)&kp[base];
    float4 kv1 = *(const float4*)&kp[base + 4];
    __syncthreads();  // previous chunk fully consumed (also covers w_s init)
    // store pre-scaled by 2.0 so inner loop computes exp(2x) directly
    float* ar = &aq_s[lr][li * 8];
    ar[0] = 2.0f * a0.x; ar[1] = 2.0f * a0.y; ar[2] = 2.0f * a0.z; ar[3] = 2.0f * a0.w;
    ar[4] = 2.0f * a1.x; ar[5] = 2.0f * a1.y; ar[6] = 2.0f * a1.z; ar[7] = 2.0f * a1.w;
    float* kr = &key_s[lr][li * 8];
    kr[0] = 2.0f * kv0.x; kr[1] = 2.0f * kv0.y; kr[2] = 2.0f * kv0.z; kr[3] = 2.0f * kv0.w;
    kr[4] = 2.0f * kv1.x; kr[5] = 2.0f * kv1.y; kr[6] = 2.0f * kv1.z; kr[7] = 2.0f * kv1.w;
    __syncthreads();

#pragma unroll
    for (int j = 0; j < 128; j += 4) {
      float4 av = *(const float4*)&aq_s[qi][j];
      float4 kv = *(const float4*)&key_s[ki][j];
      float4 wv = *(const float4*)&w_s[c * 128 + j];
      {
        float e = __expf(av.x + kv.x);  // already 2x
        float r = fast_rcp(e + 1.0f);
        acc = fmaf(wv.x, fmaf(-2.0f, r, 1.0f), acc);
      }
      {
        float e = __expf(av.y + kv.y);
        float r = fast_rcp(e + 1.0f);
        acc = fmaf(wv.y, fmaf(-2.0f, r, 1.0f), acc);
      }
      {
        float e = __expf(av.z + kv.z);
        float r = fast_rcp(e + 1.0f);
        acc = fmaf(wv.z, fmaf(-2.0f, r, 1.0f), acc);
      }
      {
        float e = __expf(av.w + kv.w);
        float r = fast_rcp(e + 1.0f);
        acc = fmaf(wv.w, fmaf(-2.0f, r, 1.0f), acc);
      }
    }
  }
  scores[(size_t)(b * 256 + q0 + qi) * 256 + k0 + ki] = acc + b_att[0];
}

// ---------------------------------------------------------------------------
// K3: per (b, 16-q tile): softmax over k (writes p to d_out), then
// context[16][512] = p @ keys[b] with keys staged 16 rows at a time in LDS.
// ---------------------------------------------------------------------------
__global__ __launch_bounds__(256) void softmax_ctx_kernel(
    const float* __restrict__ scores,  // [16][256][256]
    const float* __restrict__ keys,    // [16][256][512]
    float* __restrict__ p_out,         // [16][256][256]
    float* __restrict__ ctx)           // [4096][512]
{
  __shared__ float p_s[16][260];
  __shared__ float k_s[16 * 512];  // 32KB, reused for ctx restage

  const int b = blockIdx.y, q0 = blockIdx.x * 16;
  const int t = threadIdx.x;
  const int wv = t >> 6, lane = t & 63;
  const float LOG2E = 1.4426950408889634f;

  // Phase 1: softmax for rows q0 + wv*4 .. +3 (one wave per 4 rows)
#pragma unroll
  for (int i = 0; i < 4; ++i) {
    const int r = wv * 4 + i;
    const float* srow = &scores[(size_t)(b * 256 + q0 + r) * 256];
    float4 s4 = *(const float4*)&srow[lane * 4];
    float m = fmaxf(fmaxf(s4.x, s4.y), fmaxf(s4.z, s4.w));
#pragma unroll
    for (int msk = 32; msk; msk >>= 1) m = fmaxf(m, __shfl_xor(m, msk));
    float e0 = __expf(s4.x - m);
    float e1 = __expf(s4.y - m);
    float e2 = __expf(s4.z - m);
    float e3 = __expf(s4.w - m);
    float ssum = (e0 + e1) + (e2 + e3);
#pragma unroll
    for (int msk = 32; msk; msk >>= 1) ssum += __shfl_xor(ssum, msk);
    float rs = 1.0f / ssum;  // accurate divide, once per row
    float4 p4 = {e0 * rs, e1 * rs, e2 * rs, e3 * rs};
    *(float4*)&p_s[r][lane * 4] = p4;
    *(float4*)&p_out[(size_t)(b * 256 + q0 + r) * 256 + lane * 4] = p4;
  }

  // Phase 2: ctx tile [16][512] = p_s[16][256] @ keys[b][256][512]
  const int qg = t >> 6;  // 0..3 (wave id): rows qg*4..+3
  const int ng = t & 63;  // col group: n = ng + 64*j
  float acc[4][8] = {};
  for (int kc = 0; kc < 256; kc += 16) {
    __syncthreads();  // p_s ready (first iter) / previous k_s consumed
    const float* kbase = keys + (size_t)(b * 256 + kc) * 512;
#pragma unroll
    for (int u = 0; u < 8; ++u)
      *(float4*)&k_s[u * 1024 + t * 4] = *(const float4*)&kbase[u * 1024 + t * 4];
    __syncthreads();
#pragma unroll 4
    for (int kk = 0; kk < 16; ++kk) {
      float p0 = p_s[qg * 4 + 0][kc + kk];
      float p1 = p_s[qg * 4 + 1][kc + kk];
      float p2 = p_s[qg * 4 + 2][kc + kk];
      float p3 = p_s[qg * 4 + 3][kc + kk];
#pragma unroll
      for (int j = 0; j < 8; ++j) {
        float kv = k_s[kk * 512 + ng + j * 64];
        acc[0][j] = fmaf(p0, kv, acc[0][j]);
        acc[1][j] = fmaf(p1, kv, acc[1][j]);
        acc[2][j] = fmaf(p2, kv, acc[2][j]);
        acc[3][j] = fmaf(p3, kv, acc[3][j]);
      }
    }
  }

  // Restage ctx through LDS for coalesced stores
  __syncthreads();
#pragma unroll
  for (int i = 0; i < 4; ++i)
#pragma unroll
    for (int j = 0; j < 8; ++j)
      k_s[(qg * 4 + i) * 512 + ng + j * 64] = acc[i][j];
  __syncthreads();
  float* cb = ctx + (size_t)(b * 256 + q0) * 512;
#pragma unroll
  for (int u = 0; u < 8; ++u)
    *(float4*)&cb[u * 1024 + t * 4] = *(const float4*)&k_s[u * 1024 + t * 4];
}

// ---------------------------------------------------------------------------
extern "C" void kernel_launch(void* const* d_in, const int* in_sizes, int n_in,
                              void* d_out, int out_size, void* d_ws, size_t ws_size,
                              hipStream_t stream) {
  const float* query = (const float*)d_in[0];  // [16,256,512]
  const float* keys  = (const float*)d_in[1];  // [16,256,512]
  const float* Wq    = (const float*)d_in[2];  // [512,512]
  const float* bq    = (const float*)d_in[3];  // [512]
  const float* w_att = (const float*)d_in[4];  // [512]
  const float* b_att = (const float*)d_in[5];  // [1]
  const float* Wout  = (const float*)d_in[6];  // [1024,512]
  const float* bout  = (const float*)d_in[7];  // [512]

  float* out_tanh = (float*)d_out;                  // [4096][512]
  float* out_p    = out_tanh + (size_t)4096 * 512;  // [4096][256]

  float* ws = (float*)d_ws;
  float* aq     = ws;                  // [4096][512]  = 2,097,152 f32
  float* scores = ws + 2097152;        // [4096][256]  = 1,048,576 f32
  float* ctx    = ws + 3145728;        // [4096][512]  = 2,097,152 f32

  // K1: aq = query @ Wq + bq
  gemm_bias_f32<<<dim3(8, 64), 256, 0, stream>>>(
      query, query, 512, 512, Wq, bq, aq, 512, 512, 0);

  // K2: scores
  score_kernel<<<dim3(16, 16, 16), 256, 0, stream>>>(
      aq, keys, w_att, b_att, scores);

  // K3: softmax (writes p) + context
  softmax_ctx_kernel<<<dim3(16, 16), 256, 0, stream>>>(
      scores, keys, out_p, ctx);

  // K4: out = tanh(concat(query, ctx) @ Wout + bout)
  gemm_bias_f32<<<dim3(8, 64), 256, 0, stream>>>(
      query, ctx, 512, 512, Wout, bout, out_tanh, 512, 1024, 1);
}

// Round 2
// 207.336 us; speedup vs baseline: 1.2721x; 1.2721x over previous
//
#include <hip/hip_runtime.h>

// Problem constants: B=16, TQ=256, TK=256, QD=512, KD=512
// d_out = [ tanh_out: 16*256*512 f32 ; p: 16*256*256 f32 ]
// Identity: tanh(x) = 1 - 2/(1+e^{2x});  e^{2(a+k)} = Ea*Ek with
//   Ea = exp2(C2*a), Ek = exp2(C2*k), C2 = 2*log2(e).
// scores[b,q,k] = (sum_n w_n + b_att) - 2 * sum_n w_n / (1 + Ea[q,n]*Ek[k,n])

#define C2 2.88539008177792681f  // 2*log2(e)

__device__ __forceinline__ float fast_rcp(float x) { return __builtin_amdgcn_rcpf(x); }

// ---------------------------------------------------------------------------
// K1/K4: fp32 tiled GEMM with bias + epilogue act.
// act: 0 = none, 1 = tanh, 2 = exp2(C2 * v)   (for Ea precompute)
// A split at kSplit between A0/A1 (concat), both row stride lda.
// ---------------------------------------------------------------------------
__global__ __launch_bounds__(256) void gemm_bias_f32(
    const float* __restrict__ A0, const float* __restrict__ A1, int kSplit, int lda,
    const float* __restrict__ Bm, const float* __restrict__ bias,
    float* __restrict__ C, int N, int K, int act)
{
  __shared__ float As[16][68];
  __shared__ float Bs[16][68];
  const int t = threadIdx.x;
  const int tx = t & 15, ty = t >> 4;
  const int col0 = blockIdx.x * 64, row0 = blockIdx.y * 64;
  const int lr = t >> 2, lk = (t & 3) << 2;
  const int bkr = t >> 4, bkc = (t & 15) << 2;
  float acc[4][4] = {};

  for (int k0 = 0; k0 < K; k0 += 16) {
    const float* Asrc = (k0 < kSplit) ? A0 : A1;
    const int kc = ((k0 < kSplit) ? k0 : (k0 - kSplit)) + lk;
    float4 a4 = *(const float4*)&Asrc[(size_t)(row0 + lr) * lda + kc];
    float4 b4 = *(const float4*)&Bm[(size_t)(k0 + bkr) * N + col0 + bkc];
    __syncthreads();
    As[lk + 0][lr] = a4.x; As[lk + 1][lr] = a4.y;
    As[lk + 2][lr] = a4.z; As[lk + 3][lr] = a4.w;
    *(float4*)&Bs[bkr][bkc] = b4;
    __syncthreads();
#pragma unroll
    for (int kk = 0; kk < 16; ++kk) {
      float4 av = *(const float4*)&As[kk][ty * 4];
      float4 bv = *(const float4*)&Bs[kk][tx * 4];
      float am[4] = {av.x, av.y, av.z, av.w};
      float bm[4] = {bv.x, bv.y, bv.z, bv.w};
#pragma unroll
      for (int i = 0; i < 4; ++i)
#pragma unroll
        for (int j = 0; j < 4; ++j)
          acc[i][j] = fmaf(am[i], bm[j], acc[i][j]);
    }
  }

  float4 bb = *(const float4*)&bias[col0 + tx * 4];
  float bias4[4] = {bb.x, bb.y, bb.z, bb.w};
#pragma unroll
  for (int i = 0; i < 4; ++i) {
    float4 o;
    float* op = &o.x;
#pragma unroll
    for (int j = 0; j < 4; ++j) {
      float v = acc[i][j] + bias4[j];
      if (act == 1) {
        float e = __expf(2.0f * v);
        v = 1.0f - 2.0f * fast_rcp(e + 1.0f);
      } else if (act == 2) {
        v = exp2f(C2 * v);
      }
      op[j] = v;
    }
    *(float4*)&C[(size_t)(row0 + ty * 4 + i) * N + col0 + tx * 4] = o;
  }
}

// ---------------------------------------------------------------------------
// Kek: Ek = exp2(C2 * keys), elementwise; block 0 also reduces
//      Cout = sum(w_att) + b_att.
// ---------------------------------------------------------------------------
__global__ __launch_bounds__(256) void ek_kernel(
    const float* __restrict__ keys, float* __restrict__ Ek,
    const float* __restrict__ w_att, const float* __restrict__ b_att,
    float* __restrict__ Cout)
{
  __shared__ float red[4];
  const int t = threadIdx.x;
  const size_t i4 = (size_t)blockIdx.x * 256 + t;  // float4 index
  float4 v = ((const float4*)keys)[i4];
  float4 o;
  o.x = exp2f(C2 * v.x); o.y = exp2f(C2 * v.y);
  o.z = exp2f(C2 * v.z); o.w = exp2f(C2 * v.w);
  ((float4*)Ek)[i4] = o;

  if (blockIdx.x == 0) {
    float wsum = w_att[t] + w_att[t + 256];
#pragma unroll
    for (int m = 32; m; m >>= 1) wsum += __shfl_xor(wsum, m);
    if ((t & 63) == 0) red[t >> 6] = wsum;
    __syncthreads();
    if (t == 0) Cout[0] = red[0] + red[1] + red[2] + red[3] + b_att[0];
  }
}

// ---------------------------------------------------------------------------
// K2: scores[b,q,k] = C - 2*sum_n w_n / (1 + Ea[b,q,n]*Ek[b,k,n])
// 32x32 (q,k) tile per block, 256 threads, 2x2 register microtile.
// n staged in LDS chunks of 64 (padded rows, conflict-free).
// ---------------------------------------------------------------------------
__global__ __launch_bounds__(256) void score_kernel(
    const float* __restrict__ Ea,    // [4096][512]
    const float* __restrict__ Ek,    // [4096][512]
    const float* __restrict__ w_att, // [512]
    const float* __restrict__ Cptr,  // [1] = sum(w)+b_att
    float* __restrict__ scores)      // [16][256][256]
{
  __shared__ float ea_s[32][68];
  __shared__ float ek_s[32][68];
  __shared__ float w_s[512];

  const int b = blockIdx.z, q0 = blockIdx.y * 32, k0 = blockIdx.x * 32;
  const int t = threadIdx.x;
  w_s[t] = w_att[t];
  w_s[t + 256] = w_att[t + 256];

  const int qi = t >> 4, ki = t & 15;      // compute: rows qi,qi+16 x cols ki,ki+16
  const int lr = t >> 3, lc = (t & 7) * 8; // staging: row 0..31, col group of 8
  const float* eap = Ea + (size_t)(b * 256 + q0) * 512;
  const float* ekp = Ek + (size_t)(b * 256 + k0) * 512;

  float acc00 = 0.f, acc01 = 0.f, acc10 = 0.f, acc11 = 0.f;

#define TERM(A, Kv, Wv, accv) accv = fmaf(Wv, fast_rcp(fmaf(A, Kv, 1.0f)), accv)

  for (int c = 0; c < 8; ++c) {
    const int gb = lr * 512 + c * 64 + lc;
    float4 A0 = *(const float4*)&eap[gb];
    float4 A1 = *(const float4*)&eap[gb + 4];
    float4 K0 = *(const float4*)&ekp[gb];
    float4 K1 = *(const float4*)&ekp[gb + 4];
    __syncthreads();  // prev chunk consumed (also covers w_s init at c=0)
    *(float4*)&ea_s[lr][lc] = A0;
    *(float4*)&ea_s[lr][lc + 4] = A1;
    *(float4*)&ek_s[lr][lc] = K0;
    *(float4*)&ek_s[lr][lc + 4] = K1;
    __syncthreads();

#pragma unroll
    for (int j = 0; j < 64; j += 4) {
      float4 a0 = *(const float4*)&ea_s[qi][j];
      float4 a1 = *(const float4*)&ea_s[qi + 16][j];
      float4 k0v = *(const float4*)&ek_s[ki][j];
      float4 k1v = *(const float4*)&ek_s[ki + 16][j];
      float4 wv = *(const float4*)&w_s[c * 64 + j];
      TERM(a0.x, k0v.x, wv.x, acc00); TERM(a0.x, k1v.x, wv.x, acc01);
      TERM(a1.x, k0v.x, wv.x, acc10); TERM(a1.x, k1v.x, wv.x, acc11);
      TERM(a0.y, k0v.y, wv.y, acc00); TERM(a0.y, k1v.y, wv.y, acc01);
      TERM(a1.y, k0v.y, wv.y, acc10); TERM(a1.y, k1v.y, wv.y, acc11);
      TERM(a0.z, k0v.z, wv.z, acc00); TERM(a0.z, k1v.z, wv.z, acc01);
      TERM(a1.z, k0v.z, wv.z, acc10); TERM(a1.z, k1v.z, wv.z, acc11);
      TERM(a0.w, k0v.w, wv.w, acc00); TERM(a0.w, k1v.w, wv.w, acc01);
      TERM(a1.w, k0v.w, wv.w, acc10); TERM(a1.w, k1v.w, wv.w, acc11);
    }
  }
#undef TERM

  const float Cv = Cptr[0];
  const size_t qr = (size_t)(b * 256 + q0 + qi);
  scores[qr * 256 + k0 + ki]             = fmaf(-2.f, acc00, Cv);
  scores[qr * 256 + k0 + ki + 16]        = fmaf(-2.f, acc01, Cv);
  scores[(qr + 16) * 256 + k0 + ki]      = fmaf(-2.f, acc10, Cv);
  scores[(qr + 16) * 256 + k0 + ki + 16] = fmaf(-2.f, acc11, Cv);
}

// ---------------------------------------------------------------------------
// K3: per (b, 16-q tile): softmax over k (writes p), then ctx = p @ keys[b].
// ---------------------------------------------------------------------------
__global__ __launch_bounds__(256) void softmax_ctx_kernel(
    const float* __restrict__ scores,  // [16][256][256]
    const float* __restrict__ keys,    // [16][256][512]
    float* __restrict__ p_out,         // [16][256][256]
    float* __restrict__ ctx)           // [4096][512]
{
  __shared__ float p_s[16][260];
  __shared__ float k_s[16 * 512];

  const int b = blockIdx.y, q0 = blockIdx.x * 16;
  const int t = threadIdx.x;
  const int wv = t >> 6, lane = t & 63;

#pragma unroll
  for (int i = 0; i < 4; ++i) {
    const int r = wv * 4 + i;
    const float* srow = &scores[(size_t)(b * 256 + q0 + r) * 256];
    float4 s4 = *(const float4*)&srow[lane * 4];
    float m = fmaxf(fmaxf(s4.x, s4.y), fmaxf(s4.z, s4.w));
#pragma unroll
    for (int msk = 32; msk; msk >>= 1) m = fmaxf(m, __shfl_xor(m, msk));
    float e0 = __expf(s4.x - m);
    float e1 = __expf(s4.y - m);
    float e2 = __expf(s4.z - m);
    float e3 = __expf(s4.w - m);
    float ssum = (e0 + e1) + (e2 + e3);
#pragma unroll
    for (int msk = 32; msk; msk >>= 1) ssum += __shfl_xor(ssum, msk);
    float rs = 1.0f / ssum;
    float4 p4 = {e0 * rs, e1 * rs, e2 * rs, e3 * rs};
    *(float4*)&p_s[r][lane * 4] = p4;
    *(float4*)&p_out[(size_t)(b * 256 + q0 + r) * 256 + lane * 4] = p4;
  }

  const int qg = t >> 6;
  const int ng = t & 63;
  float acc[4][8] = {};
  for (int kc = 0; kc < 256; kc += 16) {
    __syncthreads();
    const float* kbase = keys + (size_t)(b * 256 + kc) * 512;
#pragma unroll
    for (int u = 0; u < 8; ++u)
      *(float4*)&k_s[u * 1024 + t * 4] = *(const float4*)&kbase[u * 1024 + t * 4];
    __syncthreads();
#pragma unroll 4
    for (int kk = 0; kk < 16; ++kk) {
      float p0 = p_s[qg * 4 + 0][kc + kk];
      float p1 = p_s[qg * 4 + 1][kc + kk];
      float p2 = p_s[qg * 4 + 2][kc + kk];
      float p3 = p_s[qg * 4 + 3][kc + kk];
#pragma unroll
      for (int j = 0; j < 8; ++j) {
        float kv = k_s[kk * 512 + ng + j * 64];
        acc[0][j] = fmaf(p0, kv, acc[0][j]);
        acc[1][j] = fmaf(p1, kv, acc[1][j]);
        acc[2][j] = fmaf(p2, kv, acc[2][j]);
        acc[3][j] = fmaf(p3, kv, acc[3][j]);
      }
    }
  }

  __syncthreads();
#pragma unroll
  for (int i = 0; i < 4; ++i)
#pragma unroll
    for (int j = 0; j < 8; ++j)
      k_s[(qg * 4 + i) * 512 + ng + j * 64] = acc[i][j];
  __syncthreads();
  float* cb = ctx + (size_t)(b * 256 + q0) * 512;
#pragma unroll
  for (int u = 0; u < 8; ++u)
    *(float4*)&cb[u * 1024 + t * 4] = *(const float4*)&k_s[u * 1024 + t * 4];
}

// ---------------------------------------------------------------------------
extern "C" void kernel_launch(void* const* d_in, const int* in_sizes, int n_in,
                              void* d_out, int out_size, void* d_ws, size_t ws_size,
                              hipStream_t stream) {
  const float* query = (const float*)d_in[0];
  const float* keys  = (const float*)d_in[1];
  const float* Wq    = (const float*)d_in[2];
  const float* bq    = (const float*)d_in[3];
  const float* w_att = (const float*)d_in[4];
  const float* b_att = (const float*)d_in[5];
  const float* Wout  = (const float*)d_in[6];
  const float* bout  = (const float*)d_in[7];

  float* out_tanh = (float*)d_out;                  // [4096][512]
  float* out_p    = out_tanh + (size_t)4096 * 512;  // [4096][256]

  float* ws = (float*)d_ws;
  float* Ea     = ws;                  // [4096][512]  (aliased by ctx later)
  float* Ek     = ws + 2097152;        // [4096][512]
  float* scores = ws + 4194304;        // [4096][256]
  float* Cptr   = ws + 5242880;        // [1]
  float* ctx    = Ea;                  // Ea dead after K2; safe alias

  // K1: Ea = exp2(C2 * (query @ Wq + bq))
  gemm_bias_f32<<<dim3(8, 64), 256, 0, stream>>>(
      query, query, 512, 512, Wq, bq, Ea, 512, 512, 2);

  // Kek: Ek = exp2(C2 * keys); block 0 computes Cptr = sum(w)+b_att
  ek_kernel<<<2048, 256, 0, stream>>>(keys, Ek, w_att, b_att, Cptr);

  // K2: scores
  score_kernel<<<dim3(8, 8, 16), 256, 0, stream>>>(
      Ea, Ek, w_att, Cptr, scores);

  // K3: softmax (writes p) + context
  softmax_ctx_kernel<<<dim3(16, 16), 256, 0, stream>>>(
      scores, keys, out_p, ctx);

  // K4: out = tanh(concat(query, ctx) @ Wout + bout)
  gemm_bias_f32<<<dim3(8, 64), 256, 0, stream>>>(
      query, ctx, 512, 512, Wout, bout, out_tanh, 512, 1024, 1);
}

// Round 3
// 162.618 us; speedup vs baseline: 1.6219x; 1.2750x over previous
//
#include <hip/hip_runtime.h>

// Problem constants: B=16, TQ=256, TK=256, QD=512, KD=512
// d_out = [ tanh_out: 16*256*512 f32 ; p: 16*256*256 f32 ]
// scores[b,q,k] = (sum_n w_n + b_att) - 2 * sum_n w_n / (1 + Ea[q,n]*Ek[k,n])
//   Ea = exp2(C2*aq), Ek = exp2(C2*keys), C2 = 2*log2(e)

#define C2 2.88539008177792681f

typedef unsigned short u16;
typedef short s16x8 __attribute__((ext_vector_type(8)));
typedef float f32x4 __attribute__((ext_vector_type(4)));

__device__ __forceinline__ float fast_rcp(float x) { return __builtin_amdgcn_rcpf(x); }

__device__ __forceinline__ u16 f2bf(float f) {
  union { float f; unsigned u; } v; v.f = f;
  unsigned r = v.u + 0x7fffu + ((v.u >> 16) & 1u);  // RNE (finite inputs)
  return (u16)(r >> 16);
}
__device__ __forceinline__ unsigned packbf(float a, float b) {
  return (unsigned)f2bf(a) | ((unsigned)f2bf(b) << 16);
}

// ---------------------------------------------------------------------------
// Prep: Wt[n][k] = bf16(W[k][n]);  W is [K][512] f32, Wt is [512][K] bf16.
// 32x32 tile via LDS. Tiny one-shot kernel.
// ---------------------------------------------------------------------------
__global__ __launch_bounds__(256) void transpose_w_bf16(
    const float* __restrict__ W, u16* __restrict__ Wt, int K)
{
  __shared__ u16 tile[32][40];
  const int t = threadIdx.x;
  const int n0 = blockIdx.x * 32, k0 = blockIdx.y * 32;
  const int r = t >> 3, c = (t & 7) * 4;
  float4 v = *(const float4*)&W[(size_t)(k0 + r) * 512 + n0 + c];
  tile[c + 0][r] = f2bf(v.x); tile[c + 1][r] = f2bf(v.y);
  tile[c + 2][r] = f2bf(v.z); tile[c + 3][r] = f2bf(v.w);
  __syncthreads();
  if (t < 128) {
    const int row = t >> 2, ch = (t & 3) * 8;
    unsigned p0 = (unsigned)tile[row][ch + 0] | ((unsigned)tile[row][ch + 1] << 16);
    unsigned p1 = (unsigned)tile[row][ch + 2] | ((unsigned)tile[row][ch + 3] << 16);
    unsigned p2 = (unsigned)tile[row][ch + 4] | ((unsigned)tile[row][ch + 5] << 16);
    unsigned p3 = (unsigned)tile[row][ch + 6] | ((unsigned)tile[row][ch + 7] << 16);
    *(int4*)&Wt[(size_t)(n0 + row) * K + k0 + ch] = make_int4(p0, p1, p2, p3);
  }
}

// ---------------------------------------------------------------------------
// K1/K4: bf16 MFMA GEMM. C[M][512] = act(A[M][K] @ W[K][512] + bias)
//   A fp32 (split A0/A1 at kSplit, both row-stride 512), converted to bf16
//   during LDS staging. Bt = W^T as bf16 [512 n][K k] row-major.
//   act: 1 = tanh, 2 = exp2(C2*v).
// Tile 128(M) x 64(N), BK=32, 4 waves (2x2), wave tile 64x32 (4x2 frags).
// ---------------------------------------------------------------------------
__global__ __launch_bounds__(256) void gemm_mfma_bf16(
    const float* __restrict__ A0, const float* __restrict__ A1, int kSplit,
    const u16* __restrict__ Bt, const float* __restrict__ bias,
    float* __restrict__ C, int K, int act)
{
  __shared__ u16 As[128 * 32];  // [row][k], 64 B rows
  __shared__ u16 Bs[64 * 32];   // [col][k], 64 B rows
  const int t = threadIdx.x;
  const int lane = t & 63, wid = t >> 6;
  const int wm = wid >> 1, wn = wid & 1;
  const int col0 = blockIdx.x * 64, row0 = blockIdx.y * 128;

  const int ar = t >> 1, ah = (t & 1) * 16;  // A staging: row, 16-elem half
  const int br = t >> 2, bc = (t & 3) * 8;   // B staging: col-row, 8-elem chunk
  const int fr = lane & 15, fg = (lane >> 4) * 8;

  f32x4 acc[4][2] = {};

  for (int k0 = 0; k0 < K; k0 += 32) {
    const float* Asrc; int kc;
    if (k0 < kSplit) { Asrc = A0; kc = k0; } else { Asrc = A1; kc = k0 - kSplit; }
    const float* ap = &Asrc[(size_t)(row0 + ar) * 512 + kc + ah];
    float4 av0 = *(const float4*)(ap + 0);
    float4 av1 = *(const float4*)(ap + 4);
    float4 av2 = *(const float4*)(ap + 8);
    float4 av3 = *(const float4*)(ap + 12);
    int4 bv = *(const int4*)&Bt[(size_t)(col0 + br) * K + k0 + bc];
    __syncthreads();  // previous iteration's fragment reads complete
    {
      unsigned p0 = packbf(av0.x, av0.y), p1 = packbf(av0.z, av0.w);
      unsigned p2 = packbf(av1.x, av1.y), p3 = packbf(av1.z, av1.w);
      unsigned p4 = packbf(av2.x, av2.y), p5 = packbf(av2.z, av2.w);
      unsigned p6 = packbf(av3.x, av3.y), p7 = packbf(av3.z, av3.w);
      *(int4*)&As[ar * 32 + ah + 0] = make_int4(p0, p1, p2, p3);
      *(int4*)&As[ar * 32 + ah + 8] = make_int4(p4, p5, p6, p7);
      *(int4*)&Bs[br * 32 + bc] = bv;
    }
    __syncthreads();

    s16x8 af[4], bf[2];
#pragma unroll
    for (int m = 0; m < 4; ++m)
      af[m] = *(const s16x8*)&As[(wm * 64 + m * 16 + fr) * 32 + fg];
#pragma unroll
    for (int n = 0; n < 2; ++n)
      bf[n] = *(const s16x8*)&Bs[(wn * 32 + n * 16 + fr) * 32 + fg];
#pragma unroll
    for (int m = 0; m < 4; ++m)
#pragma unroll
      for (int n = 0; n < 2; ++n)
        acc[m][n] = __builtin_amdgcn_mfma_f32_16x16x32_bf16(af[m], bf[n], acc[m][n], 0, 0, 0);
  }

  // Epilogue: C/D layout (verified): col = lane&15, row = (lane>>4)*4 + i
  const int fq = lane >> 4;
#pragma unroll
  for (int n = 0; n < 2; ++n) {
    const int col = col0 + wn * 32 + n * 16 + fr;
    const float bv = bias[col];
#pragma unroll
    for (int m = 0; m < 4; ++m) {
#pragma unroll
      for (int i = 0; i < 4; ++i) {
        const int row = row0 + wm * 64 + m * 16 + fq * 4 + i;
        float v = acc[m][n][i] + bv;
        if (act == 1) {
          float e = __expf(2.0f * v);
          v = 1.0f - 2.0f * fast_rcp(e + 1.0f);
        } else if (act == 2) {
          v = exp2f(C2 * v);
        }
        C[(size_t)row * 512 + col] = v;
      }
    }
  }
}

// ---------------------------------------------------------------------------
// Kek: Ek = exp2(C2 * keys); block 0 reduces Cout = sum(w_att) + b_att.
// ---------------------------------------------------------------------------
__global__ __launch_bounds__(256) void ek_kernel(
    const float* __restrict__ keys, float* __restrict__ Ek,
    const float* __restrict__ w_att, const float* __restrict__ b_att,
    float* __restrict__ Cout)
{
  __shared__ float red[4];
  const int t = threadIdx.x;
  const size_t i4 = (size_t)blockIdx.x * 256 + t;
  float4 v = ((const float4*)keys)[i4];
  float4 o;
  o.x = exp2f(C2 * v.x); o.y = exp2f(C2 * v.y);
  o.z = exp2f(C2 * v.z); o.w = exp2f(C2 * v.w);
  ((float4*)Ek)[i4] = o;

  if (blockIdx.x == 0) {
    float wsum = w_att[t] + w_att[t + 256];
#pragma unroll
    for (int m = 32; m; m >>= 1) wsum += __shfl_xor(wsum, m);
    if ((t & 63) == 0) red[t >> 6] = wsum;
    __syncthreads();
    if (t == 0) Cout[0] = red[0] + red[1] + red[2] + red[3] + b_att[0];
  }
}

// ---------------------------------------------------------------------------
// K2: scores = C - 2*sum_n w_n / (1 + Ea*Ek); 32x32 tile, 2x2 microtile.
// ---------------------------------------------------------------------------
__global__ __launch_bounds__(256) void score_kernel(
    const float* __restrict__ Ea, const float* __restrict__ Ek,
    const float* __restrict__ w_att, const float* __restrict__ Cptr,
    float* __restrict__ scores)
{
  __shared__ float ea_s[32][68];
  __shared__ float ek_s[32][68];
  __shared__ float w_s[512];

  const int b = blockIdx.z, q0 = blockIdx.y * 32, k0 = blockIdx.x * 32;
  const int t = threadIdx.x;
  w_s[t] = w_att[t];
  w_s[t + 256] = w_att[t + 256];

  const int qi = t >> 4, ki = t & 15;
  const int lr = t >> 3, lc = (t & 7) * 8;
  const float* eap = Ea + (size_t)(b * 256 + q0) * 512;
  const float* ekp = Ek + (size_t)(b * 256 + k0) * 512;

  float acc00 = 0.f, acc01 = 0.f, acc10 = 0.f, acc11 = 0.f;

#define TERM(A, Kv, Wv, accv) accv = fmaf(Wv, fast_rcp(fmaf(A, Kv, 1.0f)), accv)

  for (int c = 0; c < 8; ++c) {
    const int gb = lr * 512 + c * 64 + lc;
    float4 A0 = *(const float4*)&eap[gb];
    float4 A1 = *(const float4*)&eap[gb + 4];
    float4 K0 = *(const float4*)&ekp[gb];
    float4 K1 = *(const float4*)&ekp[gb + 4];
    __syncthreads();
    *(float4*)&ea_s[lr][lc] = A0;
    *(float4*)&ea_s[lr][lc + 4] = A1;
    *(float4*)&ek_s[lr][lc] = K0;
    *(float4*)&ek_s[lr][lc + 4] = K1;
    __syncthreads();

#pragma unroll
    for (int j = 0; j < 64; j += 4) {
      float4 a0 = *(const float4*)&ea_s[qi][j];
      float4 a1 = *(const float4*)&ea_s[qi + 16][j];
      float4 k0v = *(const float4*)&ek_s[ki][j];
      float4 k1v = *(const float4*)&ek_s[ki + 16][j];
      float4 wv = *(const float4*)&w_s[c * 64 + j];
      TERM(a0.x, k0v.x, wv.x, acc00); TERM(a0.x, k1v.x, wv.x, acc01);
      TERM(a1.x, k0v.x, wv.x, acc10); TERM(a1.x, k1v.x, wv.x, acc11);
      TERM(a0.y, k0v.y, wv.y, acc00); TERM(a0.y, k1v.y, wv.y, acc01);
      TERM(a1.y, k0v.y, wv.y, acc10); TERM(a1.y, k1v.y, wv.y, acc11);
      TERM(a0.z, k0v.z, wv.z, acc00); TERM(a0.z, k1v.z, wv.z, acc01);
      TERM(a1.z, k0v.z, wv.z, acc10); TERM(a1.z, k1v.z, wv.z, acc11);
      TERM(a0.w, k0v.w, wv.w, acc00); TERM(a0.w, k1v.w, wv.w, acc01);
      TERM(a1.w, k0v.w, wv.w, acc10); TERM(a1.w, k1v.w, wv.w, acc11);
    }
  }
#undef TERM

  const float Cv = Cptr[0];
  const size_t qr = (size_t)(b * 256 + q0 + qi);
  scores[qr * 256 + k0 + ki]             = fmaf(-2.f, acc00, Cv);
  scores[qr * 256 + k0 + ki + 16]        = fmaf(-2.f, acc01, Cv);
  scores[(qr + 16) * 256 + k0 + ki]      = fmaf(-2.f, acc10, Cv);
  scores[(qr + 16) * 256 + k0 + ki + 16] = fmaf(-2.f, acc11, Cv);
}

// ---------------------------------------------------------------------------
// K3: softmax over k (writes p) + ctx = p @ keys[b]  (ctx fp32, aliases Ea)
// ---------------------------------------------------------------------------
__global__ __launch_bounds__(256) void softmax_ctx_kernel(
    const float* __restrict__ scores, const float* __restrict__ keys,
    float* __restrict__ p_out, float* __restrict__ ctx)
{
  __shared__ float p_s[16][260];
  __shared__ float k_s[16 * 512];

  const int b = blockIdx.y, q0 = blockIdx.x * 16;
  const int t = threadIdx.x;
  const int wv = t >> 6, lane = t & 63;

#pragma unroll
  for (int i = 0; i < 4; ++i) {
    const int r = wv * 4 + i;
    const float* srow = &scores[(size_t)(b * 256 + q0 + r) * 256];
    float4 s4 = *(const float4*)&srow[lane * 4];
    float m = fmaxf(fmaxf(s4.x, s4.y), fmaxf(s4.z, s4.w));
#pragma unroll
    for (int msk = 32; msk; msk >>= 1) m = fmaxf(m, __shfl_xor(m, msk));
    float e0 = __expf(s4.x - m);
    float e1 = __expf(s4.y - m);
    float e2 = __expf(s4.z - m);
    float e3 = __expf(s4.w - m);
    float ssum = (e0 + e1) + (e2 + e3);
#pragma unroll
    for (int msk = 32; msk; msk >>= 1) ssum += __shfl_xor(ssum, msk);
    float rs = 1.0f / ssum;
    float4 p4 = {e0 * rs, e1 * rs, e2 * rs, e3 * rs};
    *(float4*)&p_s[r][lane * 4] = p4;
    *(float4*)&p_out[(size_t)(b * 256 + q0 + r) * 256 + lane * 4] = p4;
  }

  const int qg = t >> 6;
  const int ng = t & 63;
  float acc[4][8] = {};
  for (int kc = 0; kc < 256; kc += 16) {
    __syncthreads();
    const float* kbase = keys + (size_t)(b * 256 + kc) * 512;
#pragma unroll
    for (int u = 0; u < 8; ++u)
      *(float4*)&k_s[u * 1024 + t * 4] = *(const float4*)&kbase[u * 1024 + t * 4];
    __syncthreads();
#pragma unroll 4
    for (int kk = 0; kk < 16; ++kk) {
      float p0 = p_s[qg * 4 + 0][kc + kk];
      float p1 = p_s[qg * 4 + 1][kc + kk];
      float p2 = p_s[qg * 4 + 2][kc + kk];
      float p3 = p_s[qg * 4 + 3][kc + kk];
#pragma unroll
      for (int j = 0; j < 8; ++j) {
        float kv = k_s[kk * 512 + ng + j * 64];
        acc[0][j] = fmaf(p0, kv, acc[0][j]);
        acc[1][j] = fmaf(p1, kv, acc[1][j]);
        acc[2][j] = fmaf(p2, kv, acc[2][j]);
        acc[3][j] = fmaf(p3, kv, acc[3][j]);
      }
    }
  }

  __syncthreads();
#pragma unroll
  for (int i = 0; i < 4; ++i)
#pragma unroll
    for (int j = 0; j < 8; ++j)
      k_s[(qg * 4 + i) * 512 + ng + j * 64] = acc[i][j];
  __syncthreads();
  float* cb = ctx + (size_t)(b * 256 + q0) * 512;
#pragma unroll
  for (int u = 0; u < 8; ++u)
    *(float4*)&cb[u * 1024 + t * 4] = *(const float4*)&k_s[u * 1024 + t * 4];
}

// ---------------------------------------------------------------------------
extern "C" void kernel_launch(void* const* d_in, const int* in_sizes, int n_in,
                              void* d_out, int out_size, void* d_ws, size_t ws_size,
                              hipStream_t stream) {
  const float* query = (const float*)d_in[0];
  const float* keys  = (const float*)d_in[1];
  const float* Wq    = (const float*)d_in[2];
  const float* bq    = (const float*)d_in[3];
  const float* w_att = (const float*)d_in[4];
  const float* b_att = (const float*)d_in[5];
  const float* Wout  = (const float*)d_in[6];
  const float* bout  = (const float*)d_in[7];

  float* out_tanh = (float*)d_out;                  // [4096][512]
  float* out_p    = out_tanh + (size_t)4096 * 512;  // [4096][256]

  float* ws = (float*)d_ws;
  float* Ea     = ws;                    // [4096][512] f32; dead after K2
  float* Ek     = ws + 2097152;          // [4096][512] f32; dead after K2
  float* scores = ws + 4194304;          // [4096][256] f32; dead after K3
  float* Cptr   = ws + 5242880;          // [1]
  u16*   Wqt    = (u16*)(ws + 5242896);  // [512][512] bf16
  u16*   Woutt  = Wqt + 262144;          // [512][1024] bf16
  float* ctx    = Ea;                    // alias: Ea dead when K3 writes ctx

  // Prep: transposed bf16 weights
  transpose_w_bf16<<<dim3(16, 16), 256, 0, stream>>>(Wq, Wqt, 512);
  transpose_w_bf16<<<dim3(16, 32), 256, 0, stream>>>(Wout, Woutt, 1024);

  // Ek + Cptr
  ek_kernel<<<2048, 256, 0, stream>>>(keys, Ek, w_att, b_att, Cptr);

  // K1: Ea = exp2(C2 * (query @ Wq + bq))   [MFMA bf16]
  gemm_mfma_bf16<<<dim3(8, 32), 256, 0, stream>>>(
      query, query, 512, Wqt, bq, Ea, 512, 2);

  // K2: scores
  score_kernel<<<dim3(8, 8, 16), 256, 0, stream>>>(
      Ea, Ek, w_att, Cptr, scores);

  // K3: softmax (writes p) + context (fp32, aliased onto Ea)
  softmax_ctx_kernel<<<dim3(16, 16), 256, 0, stream>>>(
      scores, keys, out_p, ctx);

  // K4: out = tanh(concat(query, ctx) @ Wout + bout)   [MFMA bf16]
  gemm_mfma_bf16<<<dim3(8, 32), 256, 0, stream>>>(
      query, ctx, 512, Woutt, bout, out_tanh, 1024, 1);
}